// Round 13
// baseline (458.892 us; speedup 1.0000x reference)
//
#include <hip/hip_runtime.h>
#include <hip/hip_fp16.h>
#include <stdint.h>

#define V_N   50257
#define NPAN  393                    // ceil(V_N/128)
#define NCH   1024
#define MT    4096                   // B*S
#define KC    512                    // 2*N_FREQ
#define NFRQ  256
#define TWO_PI 6.28318530717958647692f

typedef _Float16 f16;
typedef __attribute__((ext_vector_type(8))) _Float16 f16x8;
typedef __attribute__((ext_vector_type(4))) float    f32x4;

// async global->LDS, 16B per lane; LDS dest = wave-uniform base + lane*16
__device__ __forceinline__ void gload_lds16(const void* g, const void* l) {
  typedef const __attribute__((address_space(1))) unsigned int* gp_t;
  typedef __attribute__((address_space(3))) unsigned int* lp_t;
  __builtin_amdgcn_global_load_lds((gp_t)(uint64_t)(uintptr_t)g,
                                   (lp_t)(uint32_t)(uintptr_t)l, 16, 0, 0);
}

// ---------------- Kernel 1: A[m][2f+e] = (e? Yi : Yr)[m][f],  Y = h @ w -------------
__global__ __launch_bounds__(256) void k1_proj(
    const float* __restrict__ h, const float* __restrict__ w, f16* __restrict__ A) {
  __shared__ __align__(16) f16 As[64 * 64];
  __shared__ __align__(16) f16 Bs[64 * 64];
  const int tid = threadIdx.x;
  const int bn0 = blockIdx.x * 64;
  const int bm0 = blockIdx.y * 64;
  const int lane = tid & 63, wid = tid >> 6;
  const int lr = lane & 15, lg = lane >> 4;
  const int wr = wid >> 1, wc = wid & 1;

  f32x4 acc[2][2];
#pragma unroll
  for (int i = 0; i < 2; ++i)
#pragma unroll
    for (int j = 0; j < 2; ++j) acc[i][j] = (f32x4){0.f, 0.f, 0.f, 0.f};

  for (int s = 0; s < NCH / 64; ++s) {
    const int k0 = s * 64;
    __syncthreads();
#pragma unroll
    for (int r = 0; r < 2; ++r) {
      int q = tid + r * 256;
      int m = q >> 3, c = q & 7;
      const float* src = h + (size_t)(bm0 + m) * NCH + k0 + c * 8;
      f32x4 v0 = *(const f32x4*)src;
      f32x4 v1 = *(const f32x4*)(src + 4);
      f16x8 pk;
#pragma unroll
      for (int e = 0; e < 4; ++e) { pk[e] = (f16)v0[e]; pk[4 + e] = (f16)v1[e]; }
      *(f16x8*)&As[m * 64 + ((c ^ (m & 7)) << 3)] = pk;
    }
#pragma unroll
    for (int r = 0; r < 2; ++r) {
      int q = tid + r * 256;
      int c = q >> 6, n = q & 63;
      int jj = bn0 + n;
      int wcol = (jj >> 1) + ((jj & 1) ? NFRQ : 0);
      f16x8 pk;
#pragma unroll
      for (int j = 0; j < 8; ++j)
        pk[j] = (f16)w[(size_t)(k0 + c * 8 + j) * KC + wcol];
      *(f16x8*)&Bs[n * 64 + ((c ^ (n & 7)) << 3)] = pk;
    }
    __syncthreads();
#pragma unroll
    for (int kk = 0; kk < 2; ++kk) {
      const int cb = kk * 4 + lg;
      f16x8 a[2], b[2];
#pragma unroll
      for (int mi = 0; mi < 2; ++mi) {
        int row = wr * 32 + mi * 16 + lr;
        a[mi] = *(const f16x8*)&As[row * 64 + ((cb ^ (row & 7)) << 3)];
      }
#pragma unroll
      for (int ni = 0; ni < 2; ++ni) {
        int col = wc * 32 + ni * 16 + lr;
        b[ni] = *(const f16x8*)&Bs[col * 64 + ((cb ^ (col & 7)) << 3)];
      }
#pragma unroll
      for (int mi = 0; mi < 2; ++mi)
#pragma unroll
        for (int ni = 0; ni < 2; ++ni)
          acc[mi][ni] = __builtin_amdgcn_mfma_f32_16x16x32_f16(a[mi], b[ni], acc[mi][ni], 0, 0, 0);
    }
  }
#pragma unroll
  for (int mi = 0; mi < 2; ++mi)
#pragma unroll
    for (int ni = 0; ni < 2; ++ni)
#pragma unroll
      for (int r = 0; r < 4; ++r) {
        int row = bm0 + wr * 32 + mi * 16 + lg * 4 + r;
        int col = bn0 + wc * 32 + ni * 16 + lr;
        A[(size_t)row * KC + col] = (f16)acc[mi][ni][r];
      }
}

// ---------------- Kernel 2: R8 (best, 373us) + NONTEMPORAL stores -------------------
// 128x128 tile, 4 waves, BK=64. A dbuf via gload_lds + counted vmcnt(4).
// B: next tile generated into REGISTERS pre-barrier, ds_written AFTER the
// post-compute barrier into the single 16KB buffer. LDS = 48KB -> 3 blocks/CU.
// Epilogue: __builtin_nontemporal_store (no L2 write-allocate RMW), row-burst order.

__device__ __forceinline__ void stage_tile(const f16* __restrict__ M, int grow0,
                                           int kt, f16* dst, int wid, int lane) {
#pragma unroll
  for (int i = 0; i < 4; ++i) {
    int idx = wid * 4 + i;
    int q = idx * 64 + lane;
    int m = q >> 3, c = q & 7;
    int cg = c ^ (m & 7);                       // source-side swizzle (rule #21)
    gload_lds16(M + (size_t)(grow0 + m) * KC + kt * 64 + cg * 8, dst + idx * 512);
  }
}

__device__ __forceinline__ void compute_tile(
    const f16* __restrict__ CA, const f16* __restrict__ CB,
    int wr, int wc, int lr, int lg, f32x4 acc[4][4]) {
#pragma unroll
  for (int kk = 0; kk < 2; ++kk) {
    const int cb = kk * 4 + lg;
    f16x8 a[4], b[4];
#pragma unroll
    for (int mi = 0; mi < 4; ++mi) {
      int row = wr * 64 + mi * 16 + lr;
      a[mi] = *(const f16x8*)&CA[row * 64 + ((cb ^ (row & 7)) << 3)];
    }
#pragma unroll
    for (int ni = 0; ni < 4; ++ni) {
      int col = wc * 64 + ni * 16 + lr;
      b[ni] = *(const f16x8*)&CB[col * 64 + ((cb ^ (col & 7)) << 3)];
    }
    __builtin_amdgcn_s_setprio(1);
#pragma unroll
    for (int mi = 0; mi < 4; ++mi)
#pragma unroll
      for (int ni = 0; ni < 4; ++ni)
        acc[mi][ni] = __builtin_amdgcn_mfma_f32_16x16x32_f16(a[mi], b[ni], acc[mi][ni], 0, 0, 0);
    __builtin_amdgcn_s_setprio(0);
  }
}

// base = e^{i*w0*((32s+16g)*t mod V)} — exact integer reduction, no chaining
__device__ __forceinline__ void seed_base(int s, int g, int t, float& br, float& bi) {
  int fb = 32 * s + 16 * g;
  int m = (fb * t) % V_N;                        // fb*t <= 480*50302 < 2^31
  float sn, cs;
  __sincosf((TWO_PI / (float)V_N) * (float)m, &sn, &cs);
  br = cs; bi = sn;
}

__device__ __forceinline__ void gen_bt(const float Tr[16], const float Ti[16],
                                       float br, float bi, f16x8 bt[4]) {
#pragma unroll
  for (int u = 0; u < 4; ++u)
#pragma unroll
    for (int p = 0; p < 4; ++p) {
      const int j = 4 * u + p;
      float re = br * Tr[j] - bi * Ti[j];      // cos(w0*(fb+j+1)*t)
      float im = br * Ti[j] + bi * Tr[j];      // sin(...)
      bt[u][2 * p]     = (f16)re;
      bt[u][2 * p + 1] = (f16)(-im);
    }
}

__device__ __forceinline__ void store_bt(f16* Bs, int nloc, int g, const f16x8 bt[4]) {
#pragma unroll
  for (int u = 0; u < 4; ++u) {
    int c = 4 * g + u;
    *(f16x8*)&Bs[nloc * 64 + ((c ^ (nloc & 7)) << 3)] = bt[u];
  }
}

__global__ __launch_bounds__(256, 3) void k2_otf5(
    const f16* __restrict__ A, float* __restrict__ out) {
  __shared__ __align__(16) f16 As0[128 * 64], As1[128 * 64];
  __shared__ __align__(16) f16 Bs[128 * 64];
  const int tid = threadIdx.x;
  // XCD bijective swizzle (12576 = 8*1572) + by-MAJOR: each XCD owns exactly 4
  // m-panels (1572 = 4*393); adjacent-bx blocks co-resident.
  const int orig = blockIdx.x;
  const int wgid = (orig & 7) * 1572 + (orig >> 3);
  const int by = wgid / 393;
  const int bx = wgid - by * 393;
  const int bn0 = bx << 7;
  const int bm0 = by << 7;
  const int lane = tid & 63, wid = tid >> 6;
  const int lr = lane & 15, lg = lane >> 4;
  const int wr = wid >> 1, wc = wid & 1;

  // ---- B-gen init: T[j] = e^{i*w0*((j+1)t mod V)}, all exact-seeded ----
  const int nloc = tid & 127;
  const int g = tid >> 7;
  int t = bn0 + nloc;
  if (t >= V_N) t -= V_N;                       // tail cols alias; never written
  const float w0 = TWO_PI / (float)V_N;
  float Tr[16], Ti[16];
#pragma unroll
  for (int j = 0; j < 16; ++j) {
    int m = ((j + 1) * t) % V_N;
    float sn, cs;
    __sincosf(w0 * (float)m, &sn, &cs);
    Tr[j] = cs; Ti[j] = sn;
  }

  f32x4 acc[4][4];
#pragma unroll
  for (int i = 0; i < 4; ++i)
#pragma unroll
    for (int j = 0; j < 4; ++j) acc[i][j] = (f32x4){0.f, 0.f, 0.f, 0.f};

  // ---- prologue: B(0) -> Bs, A(0) -> As0 ----
  {
    float br, bi;
    seed_base(0, g, t, br, bi);
    f16x8 bt[4];
    gen_bt(Tr, Ti, br, bi, bt);
    store_bt(Bs, nloc, g, bt);
  }
  stage_tile(A, bm0, 0, As0, wid, lane);

  f16x8 btn[4];                                  // next tile's B, in regs
  for (int s = 0; s < 8; ++s) {
    const bool nxt = (s < 7);
    f16* Ac = (s & 1) ? As1 : As0;
    f16* An = (s & 1) ? As0 : As1;
    if (nxt) {
      stage_tile(A, bm0, s + 1, An, wid, lane);  // 4 gloads in flight
      float br, bi;
      seed_base(s + 1, g, t, br, bi);            // exact seed, no chaining
      gen_bt(Tr, Ti, br, bi, btn);               // VALU overlaps gload latency
    }
    asm volatile("s_waitcnt lgkmcnt(0)" ::: "memory");   // B(s) ds_writes drained
    if (nxt) asm volatile("s_waitcnt vmcnt(4)" ::: "memory");  // A(s) landed
    else     asm volatile("s_waitcnt vmcnt(0)" ::: "memory");
    __builtin_amdgcn_s_barrier();
    compute_tile(Ac, Bs, wr, wc, lr, lg, acc);
    asm volatile("" ::: "memory");
    __builtin_amdgcn_s_barrier();                // all waves done reading B(s)
    if (nxt) store_bt(Bs, nloc, g, btn);         // write B(s+1) after the barrier
  }

  // ---- epilogue: nontemporal stores, row-burst order (mi, r, then ni) ----
  const float scale = 2.0f / (float)V_N;
  const bool full = (bn0 + 127 < V_N);
#pragma unroll
  for (int mi = 0; mi < 4; ++mi)
#pragma unroll
    for (int r = 0; r < 4; ++r) {
      int row = bm0 + wr * 64 + mi * 16 + lg * 4 + r;
      float* orow = out + (size_t)row * V_N;
      if (full) {
#pragma unroll
        for (int ni = 0; ni < 4; ++ni) {
          int col = bn0 + wc * 64 + ni * 16 + lr;
          __builtin_nontemporal_store(acc[mi][ni][r] * scale, &orow[col]);
        }
      } else {
#pragma unroll
        for (int ni = 0; ni < 4; ++ni) {
          int col = bn0 + wc * 64 + ni * 16 + lr;
          if (col < V_N)
            __builtin_nontemporal_store(acc[mi][ni][r] * scale, &orow[col]);
        }
      }
    }
}

extern "C" void kernel_launch(void* const* d_in, const int* in_sizes, int n_in,
                              void* d_out, int out_size, void* d_ws, size_t ws_size,
                              hipStream_t stream) {
  const float* h = (const float*)d_in[0];
  const float* w = (const float*)d_in[1];
  float* out = (float*)d_out;
  f16* A = (f16*)d_ws;                           // MT*KC*2 = 4.2 MB scratch

  dim3 blk(256);
  hipLaunchKernelGGL(k1_proj, dim3(KC / 64, MT / 64), blk, 0, stream, h, w, A);
  hipLaunchKernelGGL(k2_otf5, dim3(NPAN * 32), blk, 0, stream, A, out);
}